// Round 1
// baseline (273.781 us; speedup 1.0000x reference)
//
#include <hip/hip_runtime.h>

#define T_LEN 1024

typedef _Float16 f16x8 __attribute__((ext_vector_type(8)));
typedef __fp16   fp16x2 __attribute__((ext_vector_type(2)));
typedef float    f32x4 __attribute__((ext_vector_type(4)));

// Two waves (128 threads) per block; block owns 16 batch rows for all T steps.
// Hidden dim H=32 is SPLIT across the 2 waves (16 h-dims each) so total waves
// = 2048 = 2/SIMD (was 1024 = 1/SIMD): partner-wave issue hides the serial
// chain MFMA -> exp -> rcp -> pack that previously stalled ~65% of each step.
//
// Recurrence in r-space (unchanged math, bit-identical): h = 1 - 2r,
// r = 1/(exp2(t)+1), t = K*v, K = 2*log2(e).
//   t[c] = K*(x*Wih[c] + b[c] + rowsum(W_hh[c,:])) + sum_k (-2K*W_hh[c,k]) * r[k]
// Wave w computes c in [16w, 16w+16): one 16x16x32 MFMA (A = -2K*Whh rows,
// identity permutation), 4 exp + 4 rcp + 2 cvt per lane, then the halves are
// exchanged through a double-buffered LDS r-tile (1 barrier/step):
//   write: lane(n,q) C-frag = h-dims 16w+4q+{0..3}, col n -> ds_write_b64
//          at rbuf[p][n][16w+4q]
//   read : B-frag k = 8q+{0..7}, col n -> ds_read_b128 at rbuf[p][n][8q]
// Row padded to 40 f16 (80B) to spread write banks; reads are a lane-permuted
// linear 1KB fetch (conflict-free).
// HW trans kept deliberately (prev session: software replacements add net
// issue cycles; trans grinds in background).
__global__ __launch_bounds__(128) void rnn_fused(
    const float* __restrict__ x,      // [B, T]
    const float* __restrict__ W_ih,   // [32,1]
    const float* __restrict__ W_hh,   // [32,32]
    const float* __restrict__ b_ih,   // [32]
    const float* __restrict__ b_hh,   // [32]
    const float* __restrict__ fc_w,   // [1,32]
    const float* __restrict__ fc_b,   // [1]
    float* __restrict__ out)          // [B]
{
    const int tid  = threadIdx.x;
    const int w    = tid >> 6;   // wave id: owns h-dims [16w, 16w+16)
    const int lane = tid & 63;
    const int n = lane & 15;     // batch row within tile (B-frag col / C col)
    const int q = lane >> 4;     // quad index

    const float K = 2.88539008177792681472f;   // 2*log2(e)

    // Double-buffered r exchange tile: [buf][batch row n][k] (k padded 32->40)
    __shared__ __align__(16) _Float16 rbuf[2][16][40];

    // A fragment (identity row perm): A[row=n][k=8q+j] = -2K * Whh[16w+n][8q+j]
    f16x8 a;
#pragma unroll
    for (int j = 0; j < 8; ++j)
        a[j] = (_Float16)(-2.0f * K * W_hh[(16 * w + n) * 32 + 8 * q + j]);

    // This lane's 4 C h-dims: c = 16w + 4q + i  (C row = 4q+i, identity perm)
    // bias' = K*(b_ih + b_hh + rowsum(W_hh[c,:]))  (r-space fold)
    float wih[4], bias[4];
#pragma unroll
    for (int i = 0; i < 4; ++i) {
        int c = 16 * w + 4 * q + i;
        float rs = 0.0f;
        for (int k = 0; k < 32; ++k) rs += W_hh[c * 32 + k];
        wih[i]  = K * W_ih[c];
        bias[i] = K * (b_ih[c] + b_hh[c] + rs);
    }

    const float* xrow = x + (size_t)(blockIdx.x * 16 + n) * T_LEN;
    float4 xa = *(const float4*)xrow;   // t = 0..3 (4 lanes/row redundant -> broadcast)

    // B fragment holds r; h=0 <=> r=0.5
    f16x8 hb;
#pragma unroll
    for (int i = 0; i < 8; ++i) hb[i] = (_Float16)0.5f;

    // LDS addresses (constant per lane); buffer parity == step parity == pp&1
    _Float16* wrp = &rbuf[0][n][16 * w + 4 * q];     // 8B store target
    const _Float16* rdp = &rbuf[0][n][8 * q];        // 16B load source
    const int BUFSTRIDE = 16 * 40;                   // f16 elements per buffer

    for (int t4 = 0; t4 < T_LEN / 4; ++t4) {
        const int nt4 = (t4 < T_LEN / 4 - 1) ? t4 + 1 : t4;   // prefetch next x chunk
        float4 xn = *(const float4*)(xrow + (size_t)nt4 * 4);
#pragma unroll
        for (int pp = 0; pp < 4; ++pp) {
            const float xt = (pp == 0) ? xa.x : (pp == 1) ? xa.y : (pp == 2) ? xa.z : xa.w;
            f32x4 acc;
#pragma unroll
            for (int i = 0; i < 4; ++i)
                acc[i] = fmaf(xt, wih[i], bias[i]);   // C-init = K*(x*Wih + b + rowsum)
            acc = __builtin_amdgcn_mfma_f32_16x16x32_f16(a, hb, acc, 0, 0, 0);

            // 4 HW exps + 4 HW rcps per lane (half of the old 8+8)
            float e0 = __builtin_amdgcn_exp2f(acc[0]);
            float e1 = __builtin_amdgcn_exp2f(acc[1]);
            float e2 = __builtin_amdgcn_exp2f(acc[2]);
            float e3 = __builtin_amdgcn_exp2f(acc[3]);
            float r0 = __builtin_amdgcn_rcpf(e0 + 1.0f);
            float r1 = __builtin_amdgcn_rcpf(e1 + 1.0f);
            float r2 = __builtin_amdgcn_rcpf(e2 + 1.0f);
            float r3 = __builtin_amdgcn_rcpf(e3 + 1.0f);

            // pack r pairs: 2 x v_cvt_pkrtz_f16_f32 -> one ds_write_b64
            struct H2 { fp16x2 a, b; } hh;
            hh.a = __builtin_amdgcn_cvt_pkrtz(r0, r1);
            hh.b = __builtin_amdgcn_cvt_pkrtz(r2, r3);
            const unsigned long long wv =
                __builtin_bit_cast(unsigned long long, hh);
            *(unsigned long long*)(wrp + (pp & 1) * BUFSTRIDE) = wv;

            __syncthreads();   // halves visible; dbuf makes 1 barrier/step safe

            hb = *(const f16x8*)(rdp + (pp & 1) * BUFSTRIDE);  // ds_read_b128
        }
        xa = xn;
    }

    // Head: h = 1 - 2r; out[row] = sum_c h[c] * fc_w[c] + fc_b
    // Both waves hold the full-k hb after the final exchange; wave 0 reduces.
    if (w == 0) {
        float part = 0.0f;
#pragma unroll
        for (int i = 0; i < 8; ++i) {
            float h = fmaf(-2.0f, (float)hb[i], 1.0f);
            part = fmaf(h, fc_w[8 * q + i], part);
        }
        part += __shfl_xor(part, 16);
        part += __shfl_xor(part, 32);
        if (q == 0) out[blockIdx.x * 16 + n] = part + fc_b[0];
    }
}

extern "C" void kernel_launch(void* const* d_in, const int* in_sizes, int n_in,
                              void* d_out, int out_size, void* d_ws, size_t ws_size,
                              hipStream_t stream) {
    const float* x    = (const float*)d_in[0];
    const float* W_ih = (const float*)d_in[1];
    const float* W_hh = (const float*)d_in[2];
    const float* b_ih = (const float*)d_in[3];
    const float* b_hh = (const float*)d_in[4];
    const float* fc_w = (const float*)d_in[5];
    const float* fc_b = (const float*)d_in[6];
    float* out = (float*)d_out;

    const int B = in_sizes[0] / T_LEN;   // 16384
    rnn_fused<<<B / 16, 128, 0, stream>>>(x, W_ih, W_hh, b_ih, b_hh, fc_w, fc_b, out);
}